// Round 1
// baseline (6777.350 us; speedup 1.0000x reference)
//
#include <hip/hip_runtime.h>
#include <hip/hip_cooperative_groups.h>

namespace cg = cooperative_groups;

#define N_      800
#define C_      64
#define TRS_    40
#define SPT_    10
#define BUF_    120
#define T_      400
#define HSLOTS  128           // circular history padded to pow2 (>= BUF_)
#define KPL     13            // pairs per lane: 13*64 = 832 >= 800

// constants
#define A_F     (-0.5f)
#define OMEGA_F (10.0f)
#define G_F     (500.0f)
#define KGI_F   (5.0f)        // KG*KI
#define DT_F    (1e-4f)
// sqrt(1e-4)*100 == 1.0 to fp32 precision; noise enters with unit coefficient

// ---------------- prelude kernels ----------------

// sum of squares of sc  (norm(|sc|) == norm(sc))
__global__ void k_sumsq(const float* __restrict__ sc, float* __restrict__ sumsq) {
    __shared__ float sh[4];
    int tid = threadIdx.x;
    int idx = blockIdx.x * 256 + tid;
    float s = 0.f;
    for (int i = idx; i < N_ * N_; i += 256 * 256) { float v = sc[i]; s += v * v; }
    #pragma unroll
    for (int o = 1; o < 64; o <<= 1) s += __shfl_xor(s, o, 64);
    if ((tid & 63) == 0) sh[tid >> 6] = s;
    __syncthreads();
    if (tid == 0) atomicAdd(sumsq, sh[0] + sh[1] + sh[2] + sh[3]);
}

// detect whether delays buffer is int64 (odd words all zero) or int32
__global__ void k_detect(const int* __restrict__ dw, int* __restrict__ flag) {
    __shared__ int sh[4];
    int tid = threadIdx.x;
    int v = 0;
    for (int idx = 2 * tid + 1; idx < 800; idx += 512) v |= dw[idx];
    #pragma unroll
    for (int o = 1; o < 64; o <<= 1) v |= __shfl_xor(v, o, 64);
    if ((tid & 63) == 0) sh[tid >> 6] = v;
    __syncthreads();
    if (tid == 0) flag[0] = ((sh[0] | sh[1] | sh[2] | sh[3]) == 0) ? 1 : 0; // 1 => int64
}

// scatter hE (N,BUF) into circular layout: time s = -1-k lives at slot s & 127
__global__ void k_init_hist(const float* __restrict__ hE, float* __restrict__ xhist) {
    int idx = blockIdx.x * blockDim.x + threadIdx.x;
    if (idx < N_ * BUF_) {
        int j = idx / BUF_, k = idx - j * BUF_;
        xhist[j * HSLOTS + ((-1 - k) & (HSLOTS - 1))] = hE[idx];
    }
}

// ---------------- main persistent kernel ----------------

__global__ void __launch_bounds__(512, 1) k_main(
    const float* __restrict__ sc, const int* __restrict__ dw,
    const float* __restrict__ hx, const float* __restrict__ external,
    const float* __restrict__ noise, const float* __restrict__ lm,
    const float* __restrict__ sumsq, const int* __restrict__ flag,
    float* __restrict__ xhist, float* __restrict__ xtr, float* __restrict__ out)
{
    cg::grid_group grid = cg::this_grid();
    const int lane = threadIdx.x & 63;
    const int wave = (int)((blockIdx.x * 512 + threadIdx.x) >> 6); // 0..799
    const int i = wave;

    const float inv_norm = 1.0f / sqrtf(*sumsq);
    const int is64 = *flag;

    // per-lane register-resident row data
    float w[KPL]; int e[KPL]; int bofs[KPL];
    float rsum = 0.f;
    #pragma unroll
    for (int k = 0; k < KPL; ++k) {
        int j = k * 64 + lane;
        bool valid = (j < N_);
        int jj = valid ? j : 0;
        int base = i * N_ + jj;
        float wv = valid ? fabsf(sc[base]) * inv_norm : 0.f;
        int di = is64 ? (base << 1) : base;
        int dv = valid ? dw[di] : 0;
        w[k] = wv;
        e[k] = -1 - dv;            // slot = (t + e) & 127
        bofs[k] = jj * HSLOTS;
        rsum += wv;
    }
    #pragma unroll
    for (int o = 1; o < 64; o <<= 1) rsum += __shfl_xor(rsum, o, 64);

    // preload stimulus + noise for all 400 steps into registers (lane t' = q*64+lane)
    float ue[7], n0r[7], n1r[7];
    #pragma unroll
    for (int q = 0; q < 7; ++q) {
        int tp = q * 64 + lane;
        if (tp < T_) {
            int tr = tp / SPT_, sp = tp - tr * SPT_;
            ue[q]  = external[(i * SPT_ + sp) * TRS_ + tr];
            n0r[q] = noise[(tp * N_ + i) * 2 + 0];
            n1r[q] = noise[(tp * N_ + i) * 2 + 1];
        } else { ue[q] = 0.f; n0r[q] = 0.f; n1r[q] = 0.f; }
    }

    float x = hx[2 * i], y = hx[2 * i + 1];   // uniform across the wave

    int t = 0;
    #pragma unroll
    for (int q = 0; q < 7; ++q) {
        const int tmax = (q == 6) ? (T_ - 6 * 64) : 64;
        #pragma unroll 1
        for (int tt = 0; tt < tmax; ++tt, ++t) {
            // delayed gather + weighted sum over this lane's 13 pairs
            float acc = 0.f;
            #pragma unroll
            for (int k = 0; k < KPL; ++k) {
                int slot = (t + e[k]) & (HSLOTS - 1);
                acc += w[k] * xhist[bofs[k] + slot];
            }
            #pragma unroll
            for (int o = 1; o < 64; o <<= 1) acc += __shfl_xor(acc, o, 64);

            float u  = __shfl(ue[q],  tt, 64);
            float n0 = __shfl(n0r[q], tt, 64);
            float n1 = __shfl(n1r[q], tt, 64);

            float r2 = x * x + y * y;
            float dx = (A_F - r2) * x - OMEGA_F * y + G_F * (acc - rsum * x) + KGI_F * u;
            float dy = (A_F - r2) * y + OMEGA_F * x;
            x = x + DT_F * dx + n0;
            y = y + DT_F * dy + n1;

            if (lane == 0) {
                xhist[i * HSLOTS + (t & (HSLOTS - 1))] = x;
                if (t % SPT_ == SPT_ - 1) xtr[(t / SPT_) * N_ + i] = x;
            }
            grid.sync();
        }
    }

    // epilogue: out[c*TRS + tr] = 5 * dot(xtr[tr,:], lm[c,:]) - 2
    for (int o = wave; o < C_ * TRS_; o += 800) {
        int c = o / TRS_, tr = o - c * TRS_;
        float s = 0.f;
        #pragma unroll
        for (int k = 0; k < KPL; ++k) {
            int n = k * 64 + lane;
            if (n < N_) s += xtr[tr * N_ + n] * lm[c * N_ + n];
        }
        #pragma unroll
        for (int o2 = 1; o2 < 64; o2 <<= 1) s += __shfl_xor(s, o2, 64);
        if (lane == 0) out[o] = 5.0f * s - 2.0f;
    }
}

// ---------------- launch ----------------

extern "C" void kernel_launch(void* const* d_in, const int* in_sizes, int n_in,
                              void* d_out, int out_size, void* d_ws, size_t ws_size,
                              hipStream_t stream) {
    const float* external = (const float*)d_in[0];
    const float* hx       = (const float*)d_in[1];
    const float* hE       = (const float*)d_in[2];
    const float* sc       = (const float*)d_in[3];
    const float* lm       = (const float*)d_in[4];
    const float* noise    = (const float*)d_in[5];
    const int*   delays   = (const int*)  d_in[6];
    float* out = (float*)d_out;

    float* sumsq = (float*)d_ws;                 // ws[0]
    int*   flag  = (int*)d_ws + 1;               // ws[1]
    float* xhist = (float*)d_ws + 64;            // N_*HSLOTS floats
    float* xtr   = xhist + N_ * HSLOTS;          // TRS_*N_ floats

    hipMemsetAsync(d_ws, 0, 8, stream);
    k_sumsq<<<256, 256, 0, stream>>>(sc, sumsq);
    k_detect<<<1, 256, 0, stream>>>(delays, flag);
    k_init_hist<<<(N_ * BUF_ + 255) / 256, 256, 0, stream>>>(hE, xhist);

    void* args[] = { (void*)&sc, (void*)&delays, (void*)&hx, (void*)&external,
                     (void*)&noise, (void*)&lm, (void*)&sumsq, (void*)&flag,
                     (void*)&xhist, (void*)&xtr, (void*)&out };
    hipLaunchCooperativeKernel((const void*)k_main, dim3(100), dim3(512), args, 0, stream);
}

// Round 2
// 2736.350 us; speedup vs baseline: 2.4768x; 2.4768x over previous
//
#include <hip/hip_runtime.h>
#include <hip/hip_cooperative_groups.h>

namespace cg = cooperative_groups;

#define N_      800
#define C_      64
#define TRS_    40
#define SPT_    10
#define BUF_    120
#define T_      400
#define STRIDE  528           // per-row history stride (520 used slots, linear, no wrap)
#define KPL     13            // pairs per lane: 13*64 = 832 >= 800
#define SENT    0x7FC00BADu   // qNaN sentinel for "not yet written"

#define A_F     (-0.5f)
#define OMEGA_F (10.0f)
#define G_F     (500.0f)
#define KGI_F   (5.0f)        // KG*KI
#define DT_F    (1e-4f)
// sqrt(1e-4)*100 == 1.0f exactly; noise enters with unit coefficient

// ---------------- prelude kernels ----------------

__global__ void k_sumsq(const float* __restrict__ sc, float* __restrict__ sumsq) {
    __shared__ float sh[4];
    int tid = threadIdx.x;
    int idx = blockIdx.x * 256 + tid;
    float s = 0.f;
    for (int i = idx; i < N_ * N_; i += 256 * 256) { float v = sc[i]; s += v * v; }
    #pragma unroll
    for (int o = 1; o < 64; o <<= 1) s += __shfl_xor(s, o, 64);
    if ((tid & 63) == 0) sh[tid >> 6] = s;
    __syncthreads();
    if (tid == 0) atomicAdd(sumsq, sh[0] + sh[1] + sh[2] + sh[3]);
}

// detect whether delays buffer is int64 (odd words all zero) or int32
__global__ void k_detect(const int* __restrict__ dw, int* __restrict__ flag) {
    __shared__ int sh[4];
    int tid = threadIdx.x;
    int v = 0;
    for (int idx = 2 * tid + 1; idx < 800; idx += 512) v |= dw[idx];
    #pragma unroll
    for (int o = 1; o < 64; o <<= 1) v |= __shfl_xor(v, o, 64);
    if ((tid & 63) == 0) sh[tid >> 6] = v;
    __syncthreads();
    if (tid == 0) flag[0] = ((sh[0] | sh[1] | sh[2] | sh[3]) == 0) ? 1 : 0; // 1 => int64
}

// linear history: row j, time tau lives at slot tau+120 (tau in [-120, 399])
// slots [0,120) <- hE (hE[:,k] = x(-1-k) -> slot 119-k); slots [120,520) <- sentinel
__global__ void k_init(const float* __restrict__ hE, unsigned int* __restrict__ xh) {
    int idx = blockIdx.x * 256 + threadIdx.x;
    if (idx >= N_ * 520) return;
    int j = idx / 520, s = idx - j * 520;
    unsigned int v = (s < 120) ? __float_as_uint(hE[j * BUF_ + (119 - s)]) : SENT;
    xh[j * STRIDE + s] = v;
}

// ---------------- main persistent kernel ----------------

__global__ void __launch_bounds__(512, 1) k_main(
    const float* __restrict__ sc, const int* __restrict__ dw,
    const float* __restrict__ hx, const float* __restrict__ external,
    const float* __restrict__ noise, const float* __restrict__ lm,
    const float* __restrict__ sumsq, const int* __restrict__ flag,
    unsigned int* __restrict__ xh, float* __restrict__ xtr, float* __restrict__ out)
{
    cg::grid_group grid = cg::this_grid();
    const int lane = threadIdx.x & 63;
    const int wave = (int)((blockIdx.x * 512 + threadIdx.x) >> 6); // 0..799
    const int i = wave;

    const float inv_norm = 1.0f / sqrtf(*sumsq);
    const int is64 = *flag;

    // per-lane register-resident row data
    float w[KPL]; int ofs[KPL];
    float rsum = 0.f;
    #pragma unroll
    for (int k = 0; k < KPL; ++k) {
        int j = k * 64 + lane;
        bool valid = (j < N_);
        int jj = valid ? j : 0;
        int base = i * N_ + jj;
        float wv = valid ? fabsf(sc[base]) * inv_norm : 0.f;
        int di = is64 ? (base << 1) : base;
        int dv = valid ? dw[di] : 119;   // invalid lanes: row0, max delay (always ready)
        if (!valid) dv = 119;
        w[k] = wv;
        ofs[k] = jj * STRIDE + 119 - dv; // addr = ofs + t  -> time t-1-dv
        rsum += wv;
    }
    #pragma unroll
    for (int o = 1; o < 64; o <<= 1) rsum += __shfl_xor(rsum, o, 64);

    // preload stimulus + noise for all 400 steps into registers
    float ue[7], n0r[7], n1r[7];
    #pragma unroll
    for (int q = 0; q < 7; ++q) {
        int tp = q * 64 + lane;
        if (tp < T_) {
            int tr = tp / SPT_, sp = tp - tr * SPT_;
            ue[q]  = external[(i * SPT_ + sp) * TRS_ + tr];
            n0r[q] = noise[(tp * N_ + i) * 2 + 0];
            n1r[q] = noise[(tp * N_ + i) * 2 + 1];
        } else { ue[q] = 0.f; n0r[q] = 0.f; n1r[q] = 0.f; }
    }

    float x = hx[2 * i], y = hx[2 * i + 1];   // uniform across the wave

    int t = 0;
    int tmod = 0;
    #pragma unroll
    for (int q = 0; q < 7; ++q) {
        const int tmax = (q == 6) ? (T_ - 6 * 64) : 64;
        #pragma unroll 1
        for (int tt = 0; tt < tmax; ++tt, ++t) {
            // self-synchronizing delayed gather: poll until non-sentinel
            unsigned int vv[KPL];
            #pragma unroll
            for (int k = 0; k < KPL; ++k)
                vv[k] = __hip_atomic_load(&xh[ofs[k] + t], __ATOMIC_RELAXED,
                                          __HIP_MEMORY_SCOPE_AGENT);
            int guard = 0;
            while (true) {
                int pend = 0;
                #pragma unroll
                for (int k = 0; k < KPL; ++k) pend |= (vv[k] == SENT) ? 1 : 0;
                if (!__any(pend)) break;
                if (++guard > 100000) break;   // safety valve (never expected)
                #pragma unroll
                for (int k = 0; k < KPL; ++k)
                    if (vv[k] == SENT)
                        vv[k] = __hip_atomic_load(&xh[ofs[k] + t], __ATOMIC_RELAXED,
                                                  __HIP_MEMORY_SCOPE_AGENT);
            }
            float acc = 0.f;
            #pragma unroll
            for (int k = 0; k < KPL; ++k) acc += w[k] * __uint_as_float(vv[k]);
            #pragma unroll
            for (int o = 1; o < 64; o <<= 1) acc += __shfl_xor(acc, o, 64);

            float u  = __shfl(ue[q],  tt, 64);
            float n0 = __shfl(n0r[q], tt, 64);
            float n1 = __shfl(n1r[q], tt, 64);

            float r2 = x * x + y * y;
            float dx = (A_F - r2) * x - OMEGA_F * y + G_F * (acc - rsum * x) + KGI_F * u;
            float dy = (A_F - r2) * y + OMEGA_F * x;
            x = x + DT_F * dx + n0;
            y = y + DT_F * dy + n1;

            if (lane == 0) {
                __hip_atomic_store(&xh[i * STRIDE + t + 120], __float_as_uint(x),
                                   __ATOMIC_RELAXED, __HIP_MEMORY_SCOPE_AGENT);
                if (tmod == SPT_ - 1) xtr[(t / SPT_) * N_ + i] = x;
            }
            if (++tmod == SPT_) tmod = 0;
        }
    }

    grid.sync();   // single barrier: make xtr visible for the epilogue

    // epilogue: out[c*TRS + tr] = 5 * dot(xtr[tr,:], lm[c,:]) - 2
    for (int o = wave; o < C_ * TRS_; o += 800) {
        int c = o / TRS_, tr = o - c * TRS_;
        float s = 0.f;
        #pragma unroll
        for (int k = 0; k < KPL; ++k) {
            int n = k * 64 + lane;
            if (n < N_) s += xtr[tr * N_ + n] * lm[c * N_ + n];
        }
        #pragma unroll
        for (int o2 = 1; o2 < 64; o2 <<= 1) s += __shfl_xor(s, o2, 64);
        if (lane == 0) out[o] = 5.0f * s - 2.0f;
    }
}

// ---------------- launch ----------------

extern "C" void kernel_launch(void* const* d_in, const int* in_sizes, int n_in,
                              void* d_out, int out_size, void* d_ws, size_t ws_size,
                              hipStream_t stream) {
    const float* external = (const float*)d_in[0];
    const float* hx       = (const float*)d_in[1];
    const float* hE       = (const float*)d_in[2];
    const float* sc       = (const float*)d_in[3];
    const float* lm       = (const float*)d_in[4];
    const float* noise    = (const float*)d_in[5];
    const int*   delays   = (const int*)  d_in[6];
    float* out = (float*)d_out;

    float*        sumsq = (float*)d_ws;                    // ws[0]
    int*          flag  = (int*)d_ws + 1;                  // ws[1]
    unsigned int* xh    = (unsigned int*)d_ws + 64;        // N_*STRIDE words
    float*        xtr   = (float*)(xh + N_ * STRIDE);      // TRS_*N_ floats

    hipMemsetAsync(d_ws, 0, 8, stream);
    k_sumsq<<<256, 256, 0, stream>>>(sc, sumsq);
    k_detect<<<1, 256, 0, stream>>>(delays, flag);
    k_init<<<(N_ * 520 + 255) / 256, 256, 0, stream>>>(hE, xh);

    void* args[] = { (void*)&sc, (void*)&delays, (void*)&hx, (void*)&external,
                     (void*)&noise, (void*)&lm, (void*)&sumsq, (void*)&flag,
                     (void*)&xh, (void*)&xtr, (void*)&out };
    hipLaunchCooperativeKernel((const void*)k_main, dim3(100), dim3(512), args, 0, stream);
}